// Round 8
// baseline (64.035 us; speedup 1.0000x reference)
//
#include <hip/hip_runtime.h>
#include <hip/hip_bf16.h>

// AdaptiveTripletLoss on MI355X (gfx950).
// feats [4096,512] f32, labels [4096] i32 -> scalar f32 loss.
// R7: k_gemm gets a REAL pipeline (T3/T4 minimum-2-phase): BK=64 double
// buffer, raw s_barrier, counted vmcnt(8) -- prefetch for tile t+1 issued
// before compute of tile t, waited one full iteration later. No vmcnt(0)
// in the main loop. Plus L2-fitting XCD map (8 ib x 16 jb per XCD = 3MB
// unique < 4MiB L2; old 4x32 map = 4.5MB -> thrash, FETCH 30MB).

#define NN 4096
#define DD 512
#define NCLS 64

typedef __bf16 bf16x8 __attribute__((ext_vector_type(8)));
typedef float f32x4 __attribute__((ext_vector_type(4)));

__device__ __forceinline__ void gload_lds16(const void* g, void* l) {
  __builtin_amdgcn_global_load_lds(
      (const __attribute__((address_space(1))) void*)g,
      (__attribute__((address_space(3))) void*)l, 16, 0, 0);
}

// ---------------- kernel 1: per-class stats ----------------
__global__ __launch_bounds__(512) void k_stats(
    const float* __restrict__ feats, const int* __restrict__ labels,
    float* __restrict__ counts, float* __restrict__ cmean,
    float* __restrict__ uncert) {
  __shared__ __align__(16) int slab[NN];
  __shared__ int list[NN];
  __shared__ int chunk_off[64];
  __shared__ int sM;
  __shared__ float sred[512];
  const int c = blockIdx.x;
  const int t = threadIdx.x;
  const int lane = t & 63;
  const int wv = t >> 6;
  for (int i = t; i < NN; i += 512) slab[i] = labels[i];
  __syncthreads();
  for (int ch = wv; ch < 64; ch += 8) {
    const unsigned long long m = __ballot(slab[ch * 64 + lane] == c);
    if (lane == 0) chunk_off[ch] = __popcll(m);
  }
  __syncthreads();
  if (wv == 0) {
    const int v = chunk_off[lane];
    int inc = v;
#pragma unroll
    for (int off = 1; off < 64; off <<= 1) {
      const int o = __shfl_up(inc, off);
      if (lane >= off) inc += o;
    }
    chunk_off[lane] = inc - v;
    if (lane == 63) sM = inc;
  }
  __syncthreads();
  const int M = sM;
  for (int ch = wv; ch < 64; ch += 8) {
    const bool my = (slab[ch * 64 + lane] == c);
    const unsigned long long m = __ballot(my);
    if (my) {
      const int pos = chunk_off[ch] + __popcll(m & ((1ULL << lane) - 1ULL));
      list[pos] = ch * 64 + lane;
    }
  }
  __syncthreads();
  float s1 = 0.f, s2 = 0.f;
  int m = 0;
  for (; m + 8 <= M; m += 8) {
    float v[8];
#pragma unroll
    for (int e = 0; e < 8; ++e) v[e] = feats[(size_t)list[m + e] * DD + t];
#pragma unroll
    for (int e = 0; e < 8; ++e) { s1 += v[e]; s2 += v[e] * v[e]; }
  }
  for (; m < M; ++m) {
    const float v = feats[(size_t)list[m] * DD + t];
    s1 += v; s2 += v * v;
  }
  const float den = fmaxf((float)M, 1.f);
  const float mean = s1 / den;
  const float var = fmaxf(s2 / den - mean * mean, 0.f);
  cmean[c * DD + t] = mean;
  sred[t] = var;
  __syncthreads();
  for (int s = 256; s > 0; s >>= 1) {
    if (t < s) sred[t] += sred[t + s];
    __syncthreads();
  }
  if (t == 0) {
    uncert[c] = sred[0] / (float)DD;
    counts[c] = (float)M;
  }
}

// ---------------- kernel 2: per-row transform ----------------
__global__ __launch_bounds__(256) void k_row(
    const float* __restrict__ feats, const int* __restrict__ labels,
    const float* __restrict__ cmean, unsigned short* __restrict__ fb,
    float* __restrict__ sqb, float* __restrict__ cd2) {
  const int w = threadIdx.x >> 6;
  const int lane = threadIdx.x & 63;
  const int row = blockIdx.x * 4 + w;
  const int lab = labels[row];
  const float4* fr = (const float4*)(feats + (size_t)row * DD);
  const float4* cm = (const float4*)(cmean + (size_t)lab * DD);
  float sq = 0.f, c2 = 0.f;
  unsigned int ob[4];
#pragma unroll
  for (int h = 0; h < 2; ++h) {
    const float4 f = fr[lane * 2 + h];
    const float4 cv = cm[lane * 2 + h];
    const float fe[4] = {f.x, f.y, f.z, f.w};
    const float ce[4] = {cv.x, cv.y, cv.z, cv.w};
    unsigned short us[4];
#pragma unroll
    for (int e = 0; e < 4; ++e) {
      const __bf16 b = (__bf16)fe[e];
      const float bf = (float)b;
      sq += bf * bf;
      const float dd = fe[e] - ce[e];
      c2 += dd * dd;
      us[e] = __builtin_bit_cast(unsigned short, b);
    }
    ob[h * 2]     = (unsigned int)us[0] | ((unsigned int)us[1] << 16);
    ob[h * 2 + 1] = (unsigned int)us[2] | ((unsigned int)us[3] << 16);
  }
  *(uint4*)(fb + (size_t)row * DD + lane * 8) = make_uint4(ob[0], ob[1], ob[2], ob[3]);
#pragma unroll
  for (int off = 32; off > 0; off >>= 1) {
    sq += __shfl_xor(sq, off);
    c2 += __shfl_xor(c2, off);
  }
  if (lane == 0) {
    sqb[row] = sq;
    cd2[row] = c2;
  }
}

// ---------------- kernel 3: full fused Gram, pipelined 2-phase ----------------
// 1024 tiles of 128x128, BK=64 double-buffered. Main loop per kt:
//   STAGE(kt+1 -> other buf); vmcnt(8) [waits STAGE(kt), issued LAST iter];
//   s_barrier; MFMA on buf(kt); s_barrier.
// Loads stay in flight across barriers (T4). XCD map: 8ib x 16jb regions.
__global__ __launch_bounds__(256) void k_gemm(
    const unsigned short* __restrict__ fb, const float* __restrict__ sqb,
    const int* __restrict__ labels,
    float* __restrict__ php, float* __restrict__ phn,
    float* __restrict__ pst, float* __restrict__ pss) {
  __shared__ __align__(16) unsigned short sA[2][128 * 64];
  __shared__ __align__(16) unsigned short sB[2][128 * 64];
  __shared__ int s_labi[128], s_labj[128];
  __shared__ float s_sqi[128], s_sqj[128];

  const int bid = blockIdx.x;
  // L2-fitting XCD map: xcd = bid&7 owns an 8(ib) x 16(jb) region.
  const int xcd = bid & 7;
  const int w8 = bid >> 3;  // 0..127 within region
  const int ib = ((xcd & 3) << 3) + (w8 & 7);
  const int jb = ((xcd >> 2) << 4) + (w8 >> 3);
  const int ibase = ib << 7, jbase = jb << 7;
  const int t = threadIdx.x;
  const int lane = t & 63;
  const int w = t >> 6;
  const int wm = w >> 1, wn = w & 1;
  const int rin = lane & 15;
  const int g4 = lane >> 4;
  const int swzbyte = (g4 ^ (rin & 7)) << 4;
  const int abase = ((wm << 6) + rin) << 7;
  const int bbase = ((wn << 6) + rin) << 7;

  if (t < 128) {
    s_labi[t] = labels[ibase + t];
    s_labj[t] = labels[jbase + t];
    s_sqi[t] = sqb[ibase + t];
    s_sqj[t] = sqb[jbase + t];
  }

  // Hoisted per-thread staging descriptors: 4 A-chunks + 4 B-chunks.
  // Chunk q = r*256+t -> row q>>3, ch q&7, swizzled k-offset (ch^(row&7))*8.
  const unsigned short* gA[4];
  const unsigned short* gB[4];
  int lo[4];
#pragma unroll
  for (int r = 0; r < 4; ++r) {
    const int q = (r << 8) + t;
    const int row = q >> 3;
    const int ch = q & 7;
    const int koff = (ch ^ (row & 7)) << 3;
    gA[r] = fb + (size_t)(ibase + row) * DD + koff;
    gB[r] = fb + (size_t)(jbase + row) * DD + koff;
    lo[r] = q << 3;
  }

  f32x4 acc[4][4];
#pragma unroll
  for (int mi = 0; mi < 4; ++mi)
#pragma unroll
    for (int nj = 0; nj < 4; ++nj)
      acc[mi][nj] = (f32x4){0.f, 0.f, 0.f, 0.f};

  // prologue: stage kt=0 into buf 0
#pragma unroll
  for (int r = 0; r < 4; ++r) {
    gload_lds16(gA[r], &sA[0][lo[r]]);
    gload_lds16(gB[r], &sB[0][lo[r]]);
  }

#pragma unroll
  for (int kt = 0; kt < 8; ++kt) {
    const int cur = kt & 1;
    if (kt < 7) {
      // stage kt+1 into the other buffer (safe: it was last read in kt-1,
      // whose trailing barrier has passed)
#pragma unroll
      for (int r = 0; r < 4; ++r) {
        gload_lds16(gA[r] + ((kt + 1) << 6), &sA[cur ^ 1][lo[r]]);
        gload_lds16(gB[r] + ((kt + 1) << 6), &sB[cur ^ 1][lo[r]]);
      }
      asm volatile("s_waitcnt vmcnt(8)" ::: "memory");  // STAGE(kt) landed
    } else {
      asm volatile("s_waitcnt vmcnt(0)" ::: "memory");
    }
    __builtin_amdgcn_s_barrier();  // all waves' STAGE(kt) visible
    const char* A = (const char*)sA[cur];
    const char* B = (const char*)sB[cur];
#pragma unroll
    for (int ks = 0; ks < 2; ++ks) {
      bf16x8 af[4], bg[4];
#pragma unroll
      for (int mi = 0; mi < 4; ++mi)
        af[mi] = *(const bf16x8*)(A + abase + (mi << 11) + (swzbyte ^ (ks << 6)));
#pragma unroll
      for (int nj = 0; nj < 4; ++nj)
        bg[nj] = *(const bf16x8*)(B + bbase + (nj << 11) + (swzbyte ^ (ks << 6)));
#pragma unroll
      for (int mi = 0; mi < 4; ++mi)
#pragma unroll
        for (int nj = 0; nj < 4; ++nj)
          acc[mi][nj] = __builtin_amdgcn_mfma_f32_16x16x32_bf16(
              af[mi], bg[nj], acc[mi][nj], 0, 0, 0);
    }
    if (kt < 7) {
      asm volatile("s_waitcnt lgkmcnt(0)" ::: "memory");  // our ds_reads done
      __builtin_amdgcn_s_barrier();  // everyone done reading buf(kt)
    }
  }

  // epilogue. C/D layout: i = wm*64+mi*16+g4*4+r, j = wn*64+nj*16+rin.
  float qj[4];
  int lj[4];
#pragma unroll
  for (int nj = 0; nj < 4; ++nj) {
    const int cl = (wn << 6) + (nj << 4) + rin;
    qj[nj] = s_sqj[cl];
    lj[nj] = s_labj[cl];
  }
  const int jidx = (jb << 1) + wn;  // 64 column-partials per row
#pragma unroll
  for (int mi = 0; mi < 4; ++mi) {
#pragma unroll
    for (int r = 0; r < 4; ++r) {
      const int rl = (wm << 6) + (mi << 4) + (g4 << 2) + r;
      const float qi = s_sqi[rl];
      const int li = s_labi[rl];
      float hp = 0.f, hn = 1e30f, st = 0.f, ss = 0.f;
#pragma unroll
      for (int nj = 0; nj < 4; ++nj) {
        const float g = acc[mi][nj][r];
        float d2 = qi + qj[nj] - 2.f * g;
        d2 = fmaxf(d2, 0.f);
        const float dist = sqrtf(d2);
        const bool same = (li == lj[nj]);
        const float dp = same ? dist : 0.f;   // diag: dist~0, harmless
        hp = fmaxf(hp, dp);
        hn = fminf(hn, same ? 1e30f : dist);
        st += dist;
        ss += dp;
      }
#pragma unroll
      for (int off = 1; off < 16; off <<= 1) {
        hp = fmaxf(hp, __shfl_xor(hp, off));
        hn = fminf(hn, __shfl_xor(hn, off));
        st += __shfl_xor(st, off);
        ss += __shfl_xor(ss, off);
      }
      if (rin == 0) {
        const int grow = ibase + rl;
        php[jidx * NN + grow] = hp;
        phn[jidx * NN + grow] = hn;
        pst[jidx * NN + grow] = st;
        pss[jidx * NN + grow] = ss;
      }
    }
  }
}

// ---------------- kernel 4: combine partials, per-row margin ----------------
__global__ __launch_bounds__(256) void k_fin1(
    const int* __restrict__ labels, const float* __restrict__ counts,
    const float* __restrict__ uncert, const float* __restrict__ cd2,
    const float* __restrict__ php, const float* __restrict__ phn,
    const float* __restrict__ pst, const float* __restrict__ pss,
    float* __restrict__ pf) {
  const int t = threadIdx.x;
  const int row = blockIdx.x * 256 + t;
  float hp = 0.f, hn = 1e30f, st = 0.f, ss = 0.f;
#pragma unroll 8
  for (int j = 0; j < 64; ++j) {
    hp = fmaxf(hp, php[j * NN + row]);
    hn = fminf(hn, phn[j * NN + row]);
    st += pst[j * NN + row];
    ss += pss[j * NN + row];
  }
  const int lab = labels[row];
  const float cnt = counts[lab];
  const float pos = cnt - 1.f;
  const float neg = (float)NN - cnt;
  const float mean_pos = ss / fmaxf(pos, 1.f);
  const float mean_neg = (st - ss) / fmaxf(neg, 1.f);
  const float c2 = cd2[row];
  const float cdist = (c2 > 0.f) ? sqrtf(c2) : 0.f;
  const float margin = 0.1f + 0.1f * (mean_neg - mean_pos) + 0.1f * (cdist * uncert[lab]);
  const float ps = fmaxf(hp - hn + margin, 0.f);
  const bool valid = (pos > 0.f) && (neg > 0.f);
  float s = valid ? ps : 0.f;
  float c = valid ? 1.f : 0.f;
#pragma unroll
  for (int off = 1; off < 64; off <<= 1) {
    s += __shfl_xor(s, off);
    c += __shfl_xor(c, off);
  }
  __shared__ float ws1[4], ws2[4];
  const int lane = t & 63;
  const int wv = t >> 6;
  if (lane == 0) { ws1[wv] = s; ws2[wv] = c; }
  __syncthreads();
  if (t == 0) {
    pf[2 * blockIdx.x] = ws1[0] + ws1[1] + ws1[2] + ws1[3];
    pf[2 * blockIdx.x + 1] = ws2[0] + ws2[1] + ws2[2] + ws2[3];
  }
}

// ---------------- kernel 5: final scalar ----------------
__global__ __launch_bounds__(64) void k_fin2(const float* __restrict__ pf,
                                             float* __restrict__ out) {
  const int t = threadIdx.x;
  float s = 0.f, c = 0.f;
  if (t < 16) { s = pf[2 * t]; c = pf[2 * t + 1]; }
#pragma unroll
  for (int off = 1; off < 16; off <<= 1) {
    s += __shfl_xor(s, off);
    c += __shfl_xor(c, off);
  }
  if (t == 0) out[0] = (c > 0.f) ? (s / fmaxf(c, 1.f)) : 0.f;
}

extern "C" void kernel_launch(void* const* d_in, const int* in_sizes, int n_in,
                              void* d_out, int out_size, void* d_ws, size_t ws_size,
                              hipStream_t stream) {
  (void)in_sizes; (void)n_in; (void)out_size; (void)ws_size;
  const float* feats = (const float*)d_in[0];
  const int* labels = (const int*)d_in[1];
  char* w = (char*)d_ws;
  float* counts = (float*)(w + 0);
  float* uncert = (float*)(w + 1024);
  float* sqb    = (float*)(w + 2048);
  float* cd2    = (float*)(w + 18432);
  float* pf     = (float*)(w + 34816);          // 32 floats
  float* cmean  = (float*)(w + 36864);
  unsigned short* fb = (unsigned short*)(w + 167936);
  float* php = (float*)(w + 4362240);           // [64][4096]
  float* phn = (float*)(w + 5410816);
  float* pst = (float*)(w + 6459392);
  float* pss = (float*)(w + 7507968);

  k_stats<<<dim3(64), dim3(512), 0, stream>>>(feats, labels, counts, cmean, uncert);
  k_row<<<dim3(1024), dim3(256), 0, stream>>>(feats, labels, cmean, fb, sqb, cd2);
  k_gemm<<<dim3(1024), dim3(256), 0, stream>>>(fb, sqb, labels, php, phn, pst, pss);
  k_fin1<<<dim3(16), dim3(256), 0, stream>>>(labels, counts, uncert, cd2,
                                             php, phn, pst, pss, pf);
  k_fin2<<<dim3(1), dim3(64), 0, stream>>>(pf, (float*)d_out);
}

// Round 9
// 60.815 us; speedup vs baseline: 1.0529x; 1.0529x over previous
//
#include <hip/hip_runtime.h>
#include <hip/hip_bf16.h>

// AdaptiveTripletLoss on MI355X (gfx950).
// feats [4096,512] f32, labels [4096] i32 -> scalar f32 loss.
// R9: k_gemm re-tiled to 256x256 per block / 8 waves / 128x64 per wave
// (m201 geometry). Rationale: R2..R8 all pinned at MfmaUtil ~16% because
// 64x64-per-wave = 32 FLOP per LDS-byte -> LDS-read-feed ceiling ~20%.
// 128x64/wave = 43.7 FLOP/B + block-level A/B sharing. 256 tiles = exactly
// 1 block/CU (132KB LDS), one balanced round. Counted-vmcnt 2-phase kept.

#define NN 4096
#define DD 512
#define NCLS 64

typedef __bf16 bf16x8 __attribute__((ext_vector_type(8)));
typedef float f32x4 __attribute__((ext_vector_type(4)));

__device__ __forceinline__ void gload_lds16(const void* g, void* l) {
  __builtin_amdgcn_global_load_lds(
      (const __attribute__((address_space(1))) void*)g,
      (__attribute__((address_space(3))) void*)l, 16, 0, 0);
}

// ---------------- kernel 1: per-class stats ----------------
__global__ __launch_bounds__(512) void k_stats(
    const float* __restrict__ feats, const int* __restrict__ labels,
    float* __restrict__ counts, float* __restrict__ cmean,
    float* __restrict__ uncert) {
  __shared__ __align__(16) int slab[NN];
  __shared__ int list[NN];
  __shared__ int chunk_off[64];
  __shared__ int sM;
  __shared__ float sred[512];
  const int c = blockIdx.x;
  const int t = threadIdx.x;
  const int lane = t & 63;
  const int wv = t >> 6;
  for (int i = t; i < NN; i += 512) slab[i] = labels[i];
  __syncthreads();
  for (int ch = wv; ch < 64; ch += 8) {
    const unsigned long long m = __ballot(slab[ch * 64 + lane] == c);
    if (lane == 0) chunk_off[ch] = __popcll(m);
  }
  __syncthreads();
  if (wv == 0) {
    const int v = chunk_off[lane];
    int inc = v;
#pragma unroll
    for (int off = 1; off < 64; off <<= 1) {
      const int o = __shfl_up(inc, off);
      if (lane >= off) inc += o;
    }
    chunk_off[lane] = inc - v;
    if (lane == 63) sM = inc;
  }
  __syncthreads();
  const int M = sM;
  for (int ch = wv; ch < 64; ch += 8) {
    const bool my = (slab[ch * 64 + lane] == c);
    const unsigned long long m = __ballot(my);
    if (my) {
      const int pos = chunk_off[ch] + __popcll(m & ((1ULL << lane) - 1ULL));
      list[pos] = ch * 64 + lane;
    }
  }
  __syncthreads();
  float s1 = 0.f, s2 = 0.f;
  int m = 0;
  for (; m + 8 <= M; m += 8) {
    float v[8];
#pragma unroll
    for (int e = 0; e < 8; ++e) v[e] = feats[(size_t)list[m + e] * DD + t];
#pragma unroll
    for (int e = 0; e < 8; ++e) { s1 += v[e]; s2 += v[e] * v[e]; }
  }
  for (; m < M; ++m) {
    const float v = feats[(size_t)list[m] * DD + t];
    s1 += v; s2 += v * v;
  }
  const float den = fmaxf((float)M, 1.f);
  const float mean = s1 / den;
  const float var = fmaxf(s2 / den - mean * mean, 0.f);
  cmean[c * DD + t] = mean;
  sred[t] = var;
  __syncthreads();
  for (int s = 256; s > 0; s >>= 1) {
    if (t < s) sred[t] += sred[t + s];
    __syncthreads();
  }
  if (t == 0) {
    uncert[c] = sred[0] / (float)DD;
    counts[c] = (float)M;
  }
}

// ---------------- kernel 2: per-row transform ----------------
__global__ __launch_bounds__(256) void k_row(
    const float* __restrict__ feats, const int* __restrict__ labels,
    const float* __restrict__ cmean, unsigned short* __restrict__ fb,
    float* __restrict__ sqb, float* __restrict__ cd2) {
  const int w = threadIdx.x >> 6;
  const int lane = threadIdx.x & 63;
  const int row = blockIdx.x * 4 + w;
  const int lab = labels[row];
  const float4* fr = (const float4*)(feats + (size_t)row * DD);
  const float4* cm = (const float4*)(cmean + (size_t)lab * DD);
  float sq = 0.f, c2 = 0.f;
  unsigned int ob[4];
#pragma unroll
  for (int h = 0; h < 2; ++h) {
    const float4 f = fr[lane * 2 + h];
    const float4 cv = cm[lane * 2 + h];
    const float fe[4] = {f.x, f.y, f.z, f.w};
    const float ce[4] = {cv.x, cv.y, cv.z, cv.w};
    unsigned short us[4];
#pragma unroll
    for (int e = 0; e < 4; ++e) {
      const __bf16 b = (__bf16)fe[e];
      const float bf = (float)b;
      sq += bf * bf;
      const float dd = fe[e] - ce[e];
      c2 += dd * dd;
      us[e] = __builtin_bit_cast(unsigned short, b);
    }
    ob[h * 2]     = (unsigned int)us[0] | ((unsigned int)us[1] << 16);
    ob[h * 2 + 1] = (unsigned int)us[2] | ((unsigned int)us[3] << 16);
  }
  *(uint4*)(fb + (size_t)row * DD + lane * 8) = make_uint4(ob[0], ob[1], ob[2], ob[3]);
#pragma unroll
  for (int off = 32; off > 0; off >>= 1) {
    sq += __shfl_xor(sq, off);
    c2 += __shfl_xor(c2, off);
  }
  if (lane == 0) {
    sqb[row] = sq;
    cd2[row] = c2;
  }
}

// ---------------- kernel 3: fused Gram, 256x256 tile / 8 waves ----------------
// 256 blocks (16x16 tiles), 1/CU, one balanced round. Per wave: 128x64 out,
// 8x4 frags of 16x16x32. BK=64 double-buffered (128KB LDS), counted vmcnt(8).
// Same verified swizzle (store chunk c^(row&7), read (g4^(rin&7))^(ks<<2)).
__global__ __launch_bounds__(512, 2) void k_gemm(
    const unsigned short* __restrict__ fb, const float* __restrict__ sqb,
    const int* __restrict__ labels,
    float* __restrict__ php, float* __restrict__ phn,
    float* __restrict__ pst, float* __restrict__ pss) {
  __shared__ __align__(16) unsigned short sA[2][256 * 64];
  __shared__ __align__(16) unsigned short sB[2][256 * 64];
  __shared__ int s_labi[256], s_labj[256];
  __shared__ float s_sqi[256], s_sqj[256];

  const int bid = blockIdx.x;
  // XCD map: xcd owns a 4(ib) x 8(jb) region (12 panels * 256KB = 3MB < L2)
  const int xcd = bid & 7;
  const int w8 = bid >> 3;  // 0..31
  const int ib = ((xcd & 3) << 2) + (w8 & 3);
  const int jb = ((xcd >> 2) << 3) + (w8 >> 2);
  const int ibase = ib << 8, jbase = jb << 8;
  const int t = threadIdx.x;
  const int lane = t & 63;
  const int w = t >> 6;          // 0..7
  const int wm = w >> 2;         // 0..1  (row half)
  const int wn = w & 3;          // 0..3  (col quarter)
  const int rin = lane & 15;
  const int g4 = lane >> 4;
  const int swzbyte = (g4 ^ (rin & 7)) << 4;
  const int abase = ((wm << 7) + rin) << 7;  // (wm*128+rin)*128 bytes
  const int bbase = ((wn << 6) + rin) << 7;

  if (t < 256) {
    s_labi[t] = labels[ibase + t];
    s_labj[t] = labels[jbase + t];
    s_sqi[t] = sqb[ibase + t];
    s_sqj[t] = sqb[jbase + t];
  }

  // hoisted staging descriptors: 4 A-chunks + 4 B-chunks per thread
  const unsigned short* gA[4];
  const unsigned short* gB[4];
  int lo[4];
#pragma unroll
  for (int r = 0; r < 4; ++r) {
    const int q = (r << 9) + t;       // 0..2047
    const int row = q >> 3;           // 0..255
    const int ch = q & 7;
    const int koff = (ch ^ (row & 7)) << 3;
    gA[r] = fb + (size_t)(ibase + row) * DD + koff;
    gB[r] = fb + (size_t)(jbase + row) * DD + koff;
    lo[r] = q << 3;
  }

  f32x4 acc[8][4];
#pragma unroll
  for (int mi = 0; mi < 8; ++mi)
#pragma unroll
    for (int nj = 0; nj < 4; ++nj)
      acc[mi][nj] = (f32x4){0.f, 0.f, 0.f, 0.f};

  // prologue: stage kt=0 into buf 0
#pragma unroll
  for (int r = 0; r < 4; ++r) {
    gload_lds16(gA[r], &sA[0][lo[r]]);
    gload_lds16(gB[r], &sB[0][lo[r]]);
  }

#pragma unroll
  for (int kt = 0; kt < 8; ++kt) {
    const int cur = kt & 1;
    if (kt < 7) {
#pragma unroll
      for (int r = 0; r < 4; ++r) {
        gload_lds16(gA[r] + ((kt + 1) << 6), &sA[cur ^ 1][lo[r]]);
        gload_lds16(gB[r] + ((kt + 1) << 6), &sB[cur ^ 1][lo[r]]);
      }
      asm volatile("s_waitcnt vmcnt(8)" ::: "memory");  // STAGE(kt) landed
    } else {
      asm volatile("s_waitcnt vmcnt(0)" ::: "memory");
    }
    __builtin_amdgcn_s_barrier();
    const char* A = (const char*)sA[cur];
    const char* B = (const char*)sB[cur];
#pragma unroll
    for (int ks = 0; ks < 2; ++ks) {
      bf16x8 af[8], bg[4];
#pragma unroll
      for (int mi = 0; mi < 8; ++mi)
        af[mi] = *(const bf16x8*)(A + abase + (mi << 11) + (swzbyte ^ (ks << 6)));
#pragma unroll
      for (int nj = 0; nj < 4; ++nj)
        bg[nj] = *(const bf16x8*)(B + bbase + (nj << 11) + (swzbyte ^ (ks << 6)));
#pragma unroll
      for (int mi = 0; mi < 8; ++mi)
#pragma unroll
        for (int nj = 0; nj < 4; ++nj)
          acc[mi][nj] = __builtin_amdgcn_mfma_f32_16x16x32_bf16(
              af[mi], bg[nj], acc[mi][nj], 0, 0, 0);
    }
    if (kt < 7) {
      asm volatile("s_waitcnt lgkmcnt(0)" ::: "memory");  // ds_reads done
      __builtin_amdgcn_s_barrier();  // buf(kt) reusable
    }
  }

  // epilogue. i = wm*128 + mi*16 + g4*4 + r, j = wn*64 + nj*16 + rin.
  float qj[4];
  int lj[4];
#pragma unroll
  for (int nj = 0; nj < 4; ++nj) {
    const int cl = (wn << 6) + (nj << 4) + rin;
    qj[nj] = s_sqj[cl];
    lj[nj] = s_labj[cl];
  }
  const int jidx = (jb << 2) + wn;  // 64 column-partials per row
#pragma unroll
  for (int mi = 0; mi < 8; ++mi) {
#pragma unroll
    for (int r = 0; r < 4; ++r) {
      const int rl = (wm << 7) + (mi << 4) + (g4 << 2) + r;
      const float qi = s_sqi[rl];
      const int li = s_labi[rl];
      float hp = 0.f, hn = 1e30f, st = 0.f, ss = 0.f;
#pragma unroll
      for (int nj = 0; nj < 4; ++nj) {
        const float g = acc[mi][nj][r];
        float d2 = qi + qj[nj] - 2.f * g;
        d2 = fmaxf(d2, 0.f);
        const float dist = sqrtf(d2);
        const bool same = (li == lj[nj]);
        const float dp = same ? dist : 0.f;   // diag: dist~0, harmless
        hp = fmaxf(hp, dp);
        hn = fminf(hn, same ? 1e30f : dist);
        st += dist;
        ss += dp;
      }
#pragma unroll
      for (int off = 1; off < 16; off <<= 1) {
        hp = fmaxf(hp, __shfl_xor(hp, off));
        hn = fminf(hn, __shfl_xor(hn, off));
        st += __shfl_xor(st, off);
        ss += __shfl_xor(ss, off);
      }
      if (rin == 0) {
        const int grow = ibase + rl;
        php[jidx * NN + grow] = hp;
        phn[jidx * NN + grow] = hn;
        pst[jidx * NN + grow] = st;
        pss[jidx * NN + grow] = ss;
      }
    }
  }
}

// ---------------- kernel 4: combine partials, per-row margin ----------------
__global__ __launch_bounds__(256) void k_fin1(
    const int* __restrict__ labels, const float* __restrict__ counts,
    const float* __restrict__ uncert, const float* __restrict__ cd2,
    const float* __restrict__ php, const float* __restrict__ phn,
    const float* __restrict__ pst, const float* __restrict__ pss,
    float* __restrict__ pf) {
  const int t = threadIdx.x;
  const int row = blockIdx.x * 256 + t;
  float hp = 0.f, hn = 1e30f, st = 0.f, ss = 0.f;
#pragma unroll 8
  for (int j = 0; j < 64; ++j) {
    hp = fmaxf(hp, php[j * NN + row]);
    hn = fminf(hn, phn[j * NN + row]);
    st += pst[j * NN + row];
    ss += pss[j * NN + row];
  }
  const int lab = labels[row];
  const float cnt = counts[lab];
  const float pos = cnt - 1.f;
  const float neg = (float)NN - cnt;
  const float mean_pos = ss / fmaxf(pos, 1.f);
  const float mean_neg = (st - ss) / fmaxf(neg, 1.f);
  const float c2 = cd2[row];
  const float cdist = (c2 > 0.f) ? sqrtf(c2) : 0.f;
  const float margin = 0.1f + 0.1f * (mean_neg - mean_pos) + 0.1f * (cdist * uncert[lab]);
  const float ps = fmaxf(hp - hn + margin, 0.f);
  const bool valid = (pos > 0.f) && (neg > 0.f);
  float s = valid ? ps : 0.f;
  float c = valid ? 1.f : 0.f;
#pragma unroll
  for (int off = 1; off < 64; off <<= 1) {
    s += __shfl_xor(s, off);
    c += __shfl_xor(c, off);
  }
  __shared__ float ws1[4], ws2[4];
  const int lane = t & 63;
  const int wv = t >> 6;
  if (lane == 0) { ws1[wv] = s; ws2[wv] = c; }
  __syncthreads();
  if (t == 0) {
    pf[2 * blockIdx.x] = ws1[0] + ws1[1] + ws1[2] + ws1[3];
    pf[2 * blockIdx.x + 1] = ws2[0] + ws2[1] + ws2[2] + ws2[3];
  }
}

// ---------------- kernel 5: final scalar ----------------
__global__ __launch_bounds__(64) void k_fin2(const float* __restrict__ pf,
                                             float* __restrict__ out) {
  const int t = threadIdx.x;
  float s = 0.f, c = 0.f;
  if (t < 16) { s = pf[2 * t]; c = pf[2 * t + 1]; }
#pragma unroll
  for (int off = 1; off < 16; off <<= 1) {
    s += __shfl_xor(s, off);
    c += __shfl_xor(c, off);
  }
  if (t == 0) out[0] = (c > 0.f) ? (s / fmaxf(c, 1.f)) : 0.f;
}

extern "C" void kernel_launch(void* const* d_in, const int* in_sizes, int n_in,
                              void* d_out, int out_size, void* d_ws, size_t ws_size,
                              hipStream_t stream) {
  (void)in_sizes; (void)n_in; (void)out_size; (void)ws_size;
  const float* feats = (const float*)d_in[0];
  const int* labels = (const int*)d_in[1];
  char* w = (char*)d_ws;
  float* counts = (float*)(w + 0);
  float* uncert = (float*)(w + 1024);
  float* sqb    = (float*)(w + 2048);
  float* cd2    = (float*)(w + 18432);
  float* pf     = (float*)(w + 34816);          // 32 floats
  float* cmean  = (float*)(w + 36864);
  unsigned short* fb = (unsigned short*)(w + 167936);
  float* php = (float*)(w + 4362240);           // [64][4096]
  float* phn = (float*)(w + 5410816);
  float* pst = (float*)(w + 6459392);
  float* pss = (float*)(w + 7507968);

  k_stats<<<dim3(64), dim3(512), 0, stream>>>(feats, labels, counts, cmean, uncert);
  k_row<<<dim3(1024), dim3(256), 0, stream>>>(feats, labels, cmean, fb, sqb, cd2);
  k_gemm<<<dim3(256), dim3(512), 0, stream>>>(fb, sqb, labels, php, phn, pst, pss);
  k_fin1<<<dim3(16), dim3(256), 0, stream>>>(labels, counts, uncert, cd2,
                                             php, phn, pst, pss, pf);
  k_fin2<<<dim3(1), dim3(64), 0, stream>>>(pf, (float*)d_out);
}